// Round 4
// baseline (1324.853 us; speedup 1.0000x reference)
//
#include <hip/hip_runtime.h>

#define NB 8
#define NPTS 16384
#define NPOINT 512
#define NSAMPLE 64
#define CIN 64
#define PPT 16   // FPS points per thread (1024 threads)

typedef float v2f __attribute__((ext_vector_type(2)));

__device__ __forceinline__ v2f pk_add(v2f a, v2f b) {
    v2f d;
    asm("v_pk_add_f32 %0, %1, %2" : "=v"(d) : "v"(a), "v"(b));
    return d;
}
__device__ __forceinline__ v2f pk_mul(v2f a, v2f b) {
    v2f d;
    asm("v_pk_mul_f32 %0, %1, %2" : "=v"(d) : "v"(a), "v"(b));
    return d;
}

template <int CTRL>
__device__ __forceinline__ float dpp_f(float x) {
    int xi = __builtin_bit_cast(int, x);
    int yi = __builtin_amdgcn_update_dpp(xi, xi, CTRL, 0xF, 0xF, false);
    return __builtin_bit_cast(float, yi);
}
template <int CTRL>
__device__ __forceinline__ int dpp_i(int x) {
    return __builtin_amdgcn_update_dpp(x, x, CTRL, 0xF, 0xF, false);
}

// wave64 max reduce -> true result in lane 63
__device__ __forceinline__ float wave_max_f(float x) {
    x = fmaxf(x, dpp_f<0x111>(x));   // row_shr:1
    x = fmaxf(x, dpp_f<0x112>(x));   // row_shr:2
    x = fmaxf(x, dpp_f<0x114>(x));   // row_shr:4
    x = fmaxf(x, dpp_f<0x118>(x));   // row_shr:8
    x = fmaxf(x, dpp_f<0x142>(x));   // row_bcast:15
    x = fmaxf(x, dpp_f<0x143>(x));   // row_bcast:31
    return x;
}
__device__ __forceinline__ int wave_min_i(int x) {
    x = min(x, dpp_i<0x111>(x));
    x = min(x, dpp_i<0x112>(x));
    x = min(x, dpp_i<0x114>(x));
    x = min(x, dpp_i<0x118>(x));
    x = min(x, dpp_i<0x142>(x));
    x = min(x, dpp_i<0x143>(x));
    return x;
}

// ---------------- FPS (blocks 0..7) + feature transpose (blocks 8..2055) ----------------
__global__ __launch_bounds__(1024, 4) void fps_transpose_kernel(
    const float* __restrict__ xyz, const float* __restrict__ feats,
    int* __restrict__ fps_idx, float* __restrict__ feats_t)
{
    __shared__ float t[64][65];                    // transpose tile
    __shared__ __align__(16) int s_pair[2][16][2]; // (valbits, idx) per wave, parity-buffered

    if (blockIdx.x >= NB) {
        // -------- transpose (B, C, N) -> (B, N, C), 1024 threads --------
        int blk = blockIdx.x - NB;          // 0..2047
        int b = blk & 7;
        int tile = blk >> 3;                // 0..255
        int n0 = tile * 64;
        int cc = threadIdx.x & 63, rr = threadIdx.x >> 6;   // rr 0..15
        const float* fb = feats + (size_t)b * CIN * NPTS;
        #pragma unroll
        for (int k = 0; k < 4; ++k) {
            int c = rr + k * 16;
            t[c][cc] = fb[(size_t)c * NPTS + n0 + cc];
        }
        __syncthreads();
        float* fo = feats_t + ((size_t)b * NPTS + n0) * CIN;
        #pragma unroll
        for (int k = 0; k < 4; ++k) {
            int n = rr + k * 16;
            fo[n * CIN + cc] = t[cc][n];
        }
        return;
    }

    // -------- FPS: one block per batch, 1024 threads x 16 contiguous points --------
    const int b = blockIdx.x;
    const int tid = threadIdx.x;
    const int wv = tid >> 6, ln = tid & 63;
    const float* xb = xyz + (size_t)b * NPTS * 3;
    const int base = tid * PPT;

    // load 16 contiguous points, deinterleaved into packed pairs (24 v2f + 16 dd regs)
    v2f px2[8], py2[8], pz2[8];
    float dd[16];
    {
        const float4* xb4 = (const float4*)(xb + (size_t)base * 3);
        #pragma unroll
        for (int q = 0; q < 4; ++q) {             // 4 points per group (3 float4)
            float4 f0 = xb4[3 * q + 0];
            float4 f1 = xb4[3 * q + 1];
            float4 f2 = xb4[3 * q + 2];
            px2[2 * q + 0] = (v2f){f0.x, f0.w};
            py2[2 * q + 0] = (v2f){f0.y, f1.x};
            pz2[2 * q + 0] = (v2f){f0.z, f1.y};
            px2[2 * q + 1] = (v2f){f1.z, f2.y};
            py2[2 * q + 1] = (v2f){f1.w, f2.z};
            pz2[2 * q + 1] = (v2f){f2.x, f2.w};
        }
        #pragma unroll
        for (int k = 0; k < 16; ++k) dd[k] = 1e10f;
    }
    if (tid == 0) fps_idx[b * NPOINT] = 0;
    float cx = xb[0], cy = xb[1], cz = xb[2];     // centroid 0 = point 0
    __syncthreads();

    for (int j = 1; j < NPOINT; ++j) {
        const int p = j & 1;
        v2f ncx = (v2f){-cx, -cx};
        v2f ncy = (v2f){-cy, -cy};
        v2f ncz = (v2f){-cz, -cz};
        // ---- packed distance update + per-thread max (exact numpy rounding) ----
        float bm = -1.0f;
        #pragma unroll
        for (int k = 0; k < 8; ++k) {
            v2f dx = pk_add(px2[k], ncx);
            v2f dy = pk_add(py2[k], ncy);
            v2f dz = pk_add(pz2[k], ncz);
            v2f sx = pk_mul(dx, dx);
            v2f sy = pk_mul(dy, dy);
            v2f sz = pk_mul(dz, dz);
            v2f s1 = pk_add(sx, sy);
            v2f d2 = pk_add(s1, sz);              // per half: (dx²+dy²)+dz², each rounded
            float n0 = fminf(dd[2 * k + 0], d2.x);
            float n1 = fminf(dd[2 * k + 1], d2.y);
            dd[2 * k + 0] = n0;
            dd[2 * k + 1] = n1;
            bm = fmaxf(fmaxf(bm, n0), n1);        // -> v_max3
        }
        // ---- wave max via DPP ----
        float wm = wave_max_f(bm);
        float wmax = __builtin_bit_cast(float,
            __builtin_amdgcn_readlane(__builtin_bit_cast(int, wm), 63));
        // ---- per-thread first matching index (descending -> smallest k wins) ----
        int mi = 0x7fffffff;
        #pragma unroll
        for (int k = PPT - 1; k >= 0; --k)
            mi = (dd[k] == wmax) ? (base + k) : mi;
        // ---- wave min-index via DPP; lane 0 publishes (uniform) ----
        int rm = wave_min_i(mi);
        int wave_mi = __builtin_amdgcn_readlane(rm, 63);
        if (ln == 0) {
            s_pair[p][wv][0] = __builtin_bit_cast(int, wmax);
            s_pair[p][wv][1] = wave_mi;
        }
        __syncthreads();                          // single barrier per iteration
        // ---- cross-wave argmax over 16 slots: lane l holds slot l&15, 4-stage DPP ----
        int2 pr = *(const int2*)&s_pair[p][ln & 15][0];
        float v = __builtin_bit_cast(float, pr.x);
        int   i = pr.y;
        {
            float ov; int oi; bool tk;
            ov = dpp_f<0x111>(v); oi = dpp_i<0x111>(i);
            tk = (ov > v) || (ov == v && oi < i); v = tk ? ov : v; i = tk ? oi : i;
            ov = dpp_f<0x112>(v); oi = dpp_i<0x112>(i);
            tk = (ov > v) || (ov == v && oi < i); v = tk ? ov : v; i = tk ? oi : i;
            ov = dpp_f<0x114>(v); oi = dpp_i<0x114>(i);
            tk = (ov > v) || (ov == v && oi < i); v = tk ? ov : v; i = tk ? oi : i;
            ov = dpp_f<0x118>(v); oi = dpp_i<0x118>(i);
            tk = (ov > v) || (ov == v && oi < i); v = tk ? ov : v; i = tk ? oi : i;
        }
        int ch = __builtin_amdgcn_readlane(i, 15);   // uniform winner index
        const float* cp = xb + 3 * ch;               // uniform -> scalar loads
        cx = cp[0]; cy = cp[1]; cz = cp[2];
        if (tid == 0) fps_idx[b * NPOINT + j] = ch;
    }
}

// ---------------- ball query: one wave per centroid ----------------
__global__ __launch_bounds__(64) void ball_kernel(
    const float* __restrict__ xyz, const int* __restrict__ fps_idx, int* __restrict__ ball_idx)
{
    const float R2 = (float)(0.1 * 0.1);   // double product rounded to f32 (matches numpy)
    int blk = blockIdx.x;
    int b = blk & 7, j = blk >> 3;
    int lane = threadIdx.x;
    int cent = b * NPOINT + j;
    const float* xb = xyz + (size_t)b * NPTS * 3;
    int cidx = fps_idx[cent];
    float cx = xb[3 * cidx + 0];
    float cy = xb[3 * cidx + 1];
    float cz = xb[3 * cidx + 2];

    __shared__ int slots[64];
    int cnt = 0;
    for (int base = 0; base < NPTS; base += 64) {
        int i = base + lane;
        float dx = __fsub_rn(xb[3 * i + 0], cx);
        float dy = __fsub_rn(xb[3 * i + 1], cy);
        float dz = __fsub_rn(xb[3 * i + 2], cz);
        float d2 = __fadd_rn(__fadd_rn(__fmul_rn(dx, dx), __fmul_rn(dy, dy)), __fmul_rn(dz, dz));
        bool inb = d2 < R2;
        unsigned long long m = __ballot(inb);
        int pre = (int)__popcll(m & ((1ull << lane) - 1ull));
        int slot = cnt + pre;
        if (inb && slot < NSAMPLE) slots[slot] = i;
        cnt += (int)__popcll(m);
        if (cnt >= NSAMPLE) break;
    }
    __syncthreads();
    int first = (cnt > 0) ? slots[0] : 0;
    int v = (lane < cnt) ? slots[lane] : first;
    ball_idx[(size_t)cent * NSAMPLE + lane] = v;
}

// ---------------- gather + MLP(67->64->64->128) + maxpool: one wave per centroid ----------------
__global__ __launch_bounds__(64) void mlp_kernel(
    const float* __restrict__ xyz, const float* __restrict__ feats_t,
    const int* __restrict__ fps_idx, const int* __restrict__ ball_idx,
    const float* __restrict__ W1, const float* __restrict__ b1,
    const float* __restrict__ W2, const float* __restrict__ b2,
    const float* __restrict__ W3, const float* __restrict__ b3,
    float* __restrict__ out)
{
    int blk = blockIdx.x;
    int b = blk & 7, j = blk >> 3;
    int s = threadIdx.x;
    int cent = b * NPOINT + j;

    __shared__ float X[67][64];   // column-major: X[c][s] -> lane-contiguous, conflict-free

    int i = ball_idx[(size_t)cent * NSAMPLE + s];
    int cidx = fps_idx[cent];
    const float* cp = xyz + ((size_t)b * NPTS + cidx) * 3;
    float cx = cp[0], cy = cp[1], cz = cp[2];
    const float* pp = xyz + ((size_t)b * NPTS + i) * 3;
    X[64][s] = pp[0] - cx;
    X[65][s] = pp[1] - cy;
    X[66][s] = pp[2] - cz;
    const float4* fr = (const float4*)(feats_t + ((size_t)b * NPTS + i) * CIN);
    #pragma unroll
    for (int q = 0; q < 16; ++q) {
        float4 f = fr[q];
        X[q * 4 + 0][s] = f.x;
        X[q * 4 + 1][s] = f.y;
        X[q * 4 + 2][s] = f.z;
        X[q * 4 + 3][s] = f.w;
    }

    // layer 1: 67 -> 64.  x order = [feats(64), dxyz(3)] so W1 row = (c<64 ? c+3 : c-64)
    float acc[64];
    #pragma unroll
    for (int o = 0; o < 64; ++o) acc[o] = b1[o];
    for (int c = 0; c < 67; ++c) {
        float xc = X[c][s];
        const float* w = W1 + ((c < 64) ? (c + 3) : (c - 64)) * 64;
        #pragma unroll
        for (int o = 0; o < 64; ++o) acc[o] = fmaf(xc, w[o], acc[o]);
    }
    #pragma unroll
    for (int o = 0; o < 64; ++o) X[o][s] = fmaxf(acc[o], 0.0f);

    // layer 2: 64 -> 64
    #pragma unroll
    for (int o = 0; o < 64; ++o) acc[o] = b2[o];
    for (int c = 0; c < 64; ++c) {
        float xc = X[c][s];
        const float* w = W2 + c * 64;
        #pragma unroll
        for (int o = 0; o < 64; ++o) acc[o] = fmaf(xc, w[o], acc[o]);
    }
    #pragma unroll
    for (int o = 0; o < 64; ++o) X[o][s] = fmaxf(acc[o], 0.0f);

    // layer 3: 64 -> 128
    float h3[128];
    #pragma unroll
    for (int o = 0; o < 128; ++o) h3[o] = b3[o];
    for (int c = 0; c < 64; ++c) {
        float xc = X[c][s];
        const float* w = W3 + c * 128;
        #pragma unroll
        for (int o = 0; o < 128; ++o) h3[o] = fmaf(xc, w[o], h3[o]);
    }

    // relu + maxpool over the 64 samples (lanes)
    #pragma unroll
    for (int o = 0; o < 128; ++o) {
        float v = fmaxf(h3[o], 0.0f);
        #pragma unroll
        for (int off = 1; off < 64; off <<= 1) v = fmaxf(v, __shfl_xor(v, off));
        h3[o] = v;
    }
    if (s == 0) {
        float* op = out + (size_t)cent * 128;
        #pragma unroll
        for (int o = 0; o < 128; o += 4) {
            float4 v = make_float4(h3[o], h3[o + 1], h3[o + 2], h3[o + 3]);
            *(float4*)&op[o] = v;
        }
    }
}

extern "C" void kernel_launch(void* const* d_in, const int* in_sizes, int n_in,
                              void* d_out, int out_size, void* d_ws, size_t ws_size,
                              hipStream_t stream) {
    const float* xyz   = (const float*)d_in[0];
    const float* feats = (const float*)d_in[1];
    const float* W1 = (const float*)d_in[2];
    const float* b1 = (const float*)d_in[3];
    const float* W2 = (const float*)d_in[4];
    const float* b2 = (const float*)d_in[5];
    const float* W3 = (const float*)d_in[6];
    const float* b3 = (const float*)d_in[7];
    float* out = (float*)d_out;

    char* ws = (char*)d_ws;
    int*   fps_idx  = (int*)ws;                                   // 16 KB
    int*   ball_idx = (int*)(ws + 16384);                         // 1 MB
    float* feats_t  = (float*)(ws + 16384 + 1048576);             // 32 MB

    fps_transpose_kernel<<<NB + NB * (NPTS / 64), 1024, 0, stream>>>(xyz, feats, fps_idx, feats_t);
    ball_kernel<<<NB * NPOINT, 64, 0, stream>>>(xyz, fps_idx, ball_idx);
    mlp_kernel<<<NB * NPOINT, 64, 0, stream>>>(xyz, feats_t, fps_idx, ball_idx,
                                               W1, b1, W2, b2, W3, b3, out);
}

// Round 6
// 1189.587 us; speedup vs baseline: 1.1137x; 1.1137x over previous
//
#include <hip/hip_runtime.h>

#define NB 8
#define NPTS 16384
#define NPOINT 512
#define NSAMPLE 64
#define CIN 64

typedef float v2f __attribute__((ext_vector_type(2)));

template <int CTRL>
__device__ __forceinline__ float dpp_f(float x) {
    int xi = __builtin_bit_cast(int, x);
    int yi = __builtin_amdgcn_update_dpp(xi, xi, CTRL, 0xF, 0xF, false);
    return __builtin_bit_cast(float, yi);
}
template <int CTRL>
__device__ __forceinline__ int dpp_i(int x) {
    return __builtin_amdgcn_update_dpp(x, x, CTRL, 0xF, 0xF, false);
}

// wave64 max reduce -> true result in lane 63
__device__ __forceinline__ float wave_max_f(float x) {
    x = fmaxf(x, dpp_f<0x111>(x));   // row_shr:1
    x = fmaxf(x, dpp_f<0x112>(x));   // row_shr:2
    x = fmaxf(x, dpp_f<0x114>(x));   // row_shr:4
    x = fmaxf(x, dpp_f<0x118>(x));   // row_shr:8
    x = fmaxf(x, dpp_f<0x142>(x));   // row_bcast:15
    x = fmaxf(x, dpp_f<0x143>(x));   // row_bcast:31
    return x;
}
__device__ __forceinline__ int wave_min_i(int x) {
    x = min(x, dpp_i<0x111>(x));
    x = min(x, dpp_i<0x112>(x));
    x = min(x, dpp_i<0x114>(x));
    x = min(x, dpp_i<0x118>(x));
    x = min(x, dpp_i<0x142>(x));
    x = min(x, dpp_i<0x143>(x));
    return x;
}

#define CMB(va, ia, vb, ib) { bool t_ = ((vb) > (va)) || (((vb) == (va)) && ((ib) < (ia))); \
                              if (t_) { (va) = (vb); (ia) = (ib); } }

// ---------------- FPS (blocks 0..7) + feature transpose (blocks 8..2055) ----------------
__global__ __launch_bounds__(512) __attribute__((amdgpu_waves_per_eu(2, 2)))
void fps_transpose_kernel(
    const float* __restrict__ xyz, const float* __restrict__ feats,
    int* __restrict__ fps_idx, float* __restrict__ feats_t)
{
    __shared__ float t[64][65];                   // transpose tile
    __shared__ __align__(16) int s_pair[2][8][2]; // (valbits, idx) per wave, parity-buffered

    if (blockIdx.x >= NB) {
        // -------- transpose (B, C, N) -> (B, N, C) --------
        int blk = blockIdx.x - NB;          // 0..2047
        int b = blk & 7;
        int tile = blk >> 3;                // 0..255
        int n0 = tile * 64;
        int cc = threadIdx.x & 63, rr = threadIdx.x >> 6;   // rr 0..7
        const float* fb = feats + (size_t)b * CIN * NPTS;
        #pragma unroll
        for (int k = 0; k < 8; ++k) {
            int c = rr + k * 8;
            t[c][cc] = fb[(size_t)c * NPTS + n0 + cc];
        }
        __syncthreads();
        float* fo = feats_t + ((size_t)b * NPTS + n0) * CIN;
        #pragma unroll
        for (int k = 0; k < 8; ++k) {
            int n = rr + k * 8;
            fo[n * CIN + cc] = t[cc][n];
        }
        return;
    }

    // -------- FPS: one block per batch, 512 threads x 32 contiguous points --------
    const int b = blockIdx.x;
    const int tid = threadIdx.x;
    const int wv = tid >> 6, ln = tid & 63;
    const float* xb = xyz + (size_t)b * NPTS * 3;
    const int base = tid * 32;

    // load 32 contiguous points, deinterleaved into packed pairs
    v2f px2[16], py2[16], pz2[16], dd2[16];
    {
        const float4* xb4 = (const float4*)(xb + (size_t)base * 3);
        #pragma unroll
        for (int q = 0; q < 8; ++q) {             // 4 points per group (3 float4)
            float4 f0 = xb4[3 * q + 0];
            float4 f1 = xb4[3 * q + 1];
            float4 f2 = xb4[3 * q + 2];
            px2[2 * q + 0] = (v2f){f0.x, f0.w};
            py2[2 * q + 0] = (v2f){f0.y, f1.x};
            pz2[2 * q + 0] = (v2f){f0.z, f1.y};
            px2[2 * q + 1] = (v2f){f1.z, f2.y};
            py2[2 * q + 1] = (v2f){f1.w, f2.z};
            pz2[2 * q + 1] = (v2f){f2.x, f2.w};
        }
        #pragma unroll
        for (int k = 0; k < 16; ++k) dd2[k] = (v2f){1e10f, 1e10f};
    }
    if (tid == 0) fps_idx[b * NPOINT] = 0;
    float cx = xb[0], cy = xb[1], cz = xb[2];     // centroid 0 = point 0
    __syncthreads();

    for (int j = 1; j < NPOINT; ++j) {
        #pragma clang fp contract(off)
        const int p = j & 1;
        v2f ncx = (v2f){-cx, -cx};
        v2f ncy = (v2f){-cy, -cy};
        v2f ncz = (v2f){-cz, -cz};
        // ---- packed distance update + per-thread max (exact numpy rounding) ----
        float bm = -1.0f;
        #pragma unroll
        for (int k = 0; k < 16; ++k) {
            v2f dx = px2[k] + ncx;                // a + (-c) == a - c exactly
            v2f dy = py2[k] + ncy;
            v2f dz = pz2[k] + ncz;
            v2f s1 = dx * dx + dy * dy;           // contract off: mul,mul,add each rounded
            v2f d2 = s1 + dz * dz;                // (dx²+dy²)+dz² — numpy association
            v2f nd = __builtin_elementwise_min(dd2[k], d2);
            dd2[k] = nd;
            bm = fmaxf(bm, fmaxf(nd.x, nd.y));    // -> v_max3
        }
        // ---- wave max via DPP ----
        float wm = wave_max_f(bm);
        float wmax = __builtin_bit_cast(float,
            __builtin_amdgcn_readlane(__builtin_bit_cast(int, wm), 63));
        // ---- per-thread first matching sub-index (descending -> smallest wins) ----
        int mk = 64;
        #pragma unroll
        for (int k = 15; k >= 0; --k) {
            mk = (dd2[k].y == wmax) ? (2 * k + 1) : mk;   // inline-const cndmask
            mk = (dd2[k].x == wmax) ? (2 * k)     : mk;
        }
        int mi = (mk == 64) ? 0x7fffffff : (base + mk);
        // ---- wave min-index via DPP; lane 0 publishes (uniform pair) ----
        int rm = wave_min_i(mi);
        int wave_mi = __builtin_amdgcn_readlane(rm, 63);
        if (ln == 0) {
            s_pair[p][wv][0] = __builtin_bit_cast(int, wmax);
            s_pair[p][wv][1] = wave_mi;
        }
        __syncthreads();                          // single barrier per iteration
        // ---- cross-wave argmax over 8 slots (redundant on all threads) ----
        int4 q0 = *(const int4*)&s_pair[p][0][0];
        int4 q1 = *(const int4*)&s_pair[p][2][0];
        int4 q2 = *(const int4*)&s_pair[p][4][0];
        int4 q3 = *(const int4*)&s_pair[p][6][0];
        float v0 = __builtin_bit_cast(float, q0.x); int i0 = q0.y;
        float v1 = __builtin_bit_cast(float, q0.z); int i1 = q0.w;
        float v2 = __builtin_bit_cast(float, q1.x); int i2 = q1.y;
        float v3 = __builtin_bit_cast(float, q1.z); int i3 = q1.w;
        float v4 = __builtin_bit_cast(float, q2.x); int i4 = q2.y;
        float v5 = __builtin_bit_cast(float, q2.z); int i5 = q2.w;
        float v6 = __builtin_bit_cast(float, q3.x); int i6 = q3.y;
        float v7 = __builtin_bit_cast(float, q3.z); int i7 = q3.w;
        CMB(v0, i0, v1, i1); CMB(v2, i2, v3, i3);
        CMB(v4, i4, v5, i5); CMB(v6, i6, v7, i7);
        CMB(v0, i0, v2, i2); CMB(v4, i4, v6, i6);
        CMB(v0, i0, v4, i4);
        int ch = __builtin_amdgcn_readfirstlane(i0);
        const float* cp = xb + 3 * ch;            // uniform -> scalar loads
        cx = cp[0]; cy = cp[1]; cz = cp[2];
        if (tid == 0) fps_idx[b * NPOINT + j] = ch;
    }
}

// ---------------- ball query: one wave per centroid ----------------
__global__ __launch_bounds__(64) void ball_kernel(
    const float* __restrict__ xyz, const int* __restrict__ fps_idx, int* __restrict__ ball_idx)
{
    const float R2 = (float)(0.1 * 0.1);   // double product rounded to f32 (matches numpy)
    int blk = blockIdx.x;
    int b = blk & 7, j = blk >> 3;
    int lane = threadIdx.x;
    int cent = b * NPOINT + j;
    const float* xb = xyz + (size_t)b * NPTS * 3;
    int cidx = fps_idx[cent];
    float cx = xb[3 * cidx + 0];
    float cy = xb[3 * cidx + 1];
    float cz = xb[3 * cidx + 2];

    __shared__ int slots[64];
    int cnt = 0;
    for (int base = 0; base < NPTS; base += 64) {
        int i = base + lane;
        float dx = __fsub_rn(xb[3 * i + 0], cx);
        float dy = __fsub_rn(xb[3 * i + 1], cy);
        float dz = __fsub_rn(xb[3 * i + 2], cz);
        float d2 = __fadd_rn(__fadd_rn(__fmul_rn(dx, dx), __fmul_rn(dy, dy)), __fmul_rn(dz, dz));
        bool inb = d2 < R2;
        unsigned long long m = __ballot(inb);
        int pre = (int)__popcll(m & ((1ull << lane) - 1ull));
        int slot = cnt + pre;
        if (inb && slot < NSAMPLE) slots[slot] = i;
        cnt += (int)__popcll(m);
        if (cnt >= NSAMPLE) break;
    }
    __syncthreads();
    int first = (cnt > 0) ? slots[0] : 0;
    int v = (lane < cnt) ? slots[lane] : first;
    ball_idx[(size_t)cent * NSAMPLE + lane] = v;
}

// ---------------- gather + MLP(67->64->64->128) + maxpool: one wave per centroid ----------------
__global__ __launch_bounds__(64) void mlp_kernel(
    const float* __restrict__ xyz, const float* __restrict__ feats_t,
    const int* __restrict__ fps_idx, const int* __restrict__ ball_idx,
    const float* __restrict__ W1, const float* __restrict__ b1,
    const float* __restrict__ W2, const float* __restrict__ b2,
    const float* __restrict__ W3, const float* __restrict__ b3,
    float* __restrict__ out)
{
    int blk = blockIdx.x;
    int b = blk & 7, j = blk >> 3;
    int s = threadIdx.x;
    int cent = b * NPOINT + j;

    __shared__ float X[67][64];   // column-major: X[c][s] -> lane-contiguous, conflict-free

    int i = ball_idx[(size_t)cent * NSAMPLE + s];
    int cidx = fps_idx[cent];
    const float* cp = xyz + ((size_t)b * NPTS + cidx) * 3;
    float cx = cp[0], cy = cp[1], cz = cp[2];
    const float* pp = xyz + ((size_t)b * NPTS + i) * 3;
    X[64][s] = pp[0] - cx;
    X[65][s] = pp[1] - cy;
    X[66][s] = pp[2] - cz;
    const float4* fr = (const float4*)(feats_t + ((size_t)b * NPTS + i) * CIN);
    #pragma unroll
    for (int q = 0; q < 16; ++q) {
        float4 f = fr[q];
        X[q * 4 + 0][s] = f.x;
        X[q * 4 + 1][s] = f.y;
        X[q * 4 + 2][s] = f.z;
        X[q * 4 + 3][s] = f.w;
    }

    // layer 1: 67 -> 64.  x order = [feats(64), dxyz(3)] so W1 row = (c<64 ? c+3 : c-64)
    float acc[64];
    #pragma unroll
    for (int o = 0; o < 64; ++o) acc[o] = b1[o];
    for (int c = 0; c < 67; ++c) {
        float xc = X[c][s];
        const float* w = W1 + ((c < 64) ? (c + 3) : (c - 64)) * 64;
        #pragma unroll
        for (int o = 0; o < 64; ++o) acc[o] = fmaf(xc, w[o], acc[o]);
    }
    #pragma unroll
    for (int o = 0; o < 64; ++o) X[o][s] = fmaxf(acc[o], 0.0f);

    // layer 2: 64 -> 64
    #pragma unroll
    for (int o = 0; o < 64; ++o) acc[o] = b2[o];
    for (int c = 0; c < 64; ++c) {
        float xc = X[c][s];
        const float* w = W2 + c * 64;
        #pragma unroll
        for (int o = 0; o < 64; ++o) acc[o] = fmaf(xc, w[o], acc[o]);
    }
    #pragma unroll
    for (int o = 0; o < 64; ++o) X[o][s] = fmaxf(acc[o], 0.0f);

    // layer 3: 64 -> 128
    float h3[128];
    #pragma unroll
    for (int o = 0; o < 128; ++o) h3[o] = b3[o];
    for (int c = 0; c < 64; ++c) {
        float xc = X[c][s];
        const float* w = W3 + c * 128;
        #pragma unroll
        for (int o = 0; o < 128; ++o) h3[o] = fmaf(xc, w[o], h3[o]);
    }

    // relu + maxpool over the 64 samples (lanes)
    #pragma unroll
    for (int o = 0; o < 128; ++o) {
        float v = fmaxf(h3[o], 0.0f);
        #pragma unroll
        for (int off = 1; off < 64; off <<= 1) v = fmaxf(v, __shfl_xor(v, off));
        h3[o] = v;
    }
    if (s == 0) {
        float* op = out + (size_t)cent * 128;
        #pragma unroll
        for (int o = 0; o < 128; o += 4) {
            float4 v = make_float4(h3[o], h3[o + 1], h3[o + 2], h3[o + 3]);
            *(float4*)&op[o] = v;
        }
    }
}

extern "C" void kernel_launch(void* const* d_in, const int* in_sizes, int n_in,
                              void* d_out, int out_size, void* d_ws, size_t ws_size,
                              hipStream_t stream) {
    const float* xyz   = (const float*)d_in[0];
    const float* feats = (const float*)d_in[1];
    const float* W1 = (const float*)d_in[2];
    const float* b1 = (const float*)d_in[3];
    const float* W2 = (const float*)d_in[4];
    const float* b2 = (const float*)d_in[5];
    const float* W3 = (const float*)d_in[6];
    const float* b3 = (const float*)d_in[7];
    float* out = (float*)d_out;

    char* ws = (char*)d_ws;
    int*   fps_idx  = (int*)ws;                                   // 16 KB
    int*   ball_idx = (int*)(ws + 16384);                         // 1 MB
    float* feats_t  = (float*)(ws + 16384 + 1048576);             // 32 MB

    fps_transpose_kernel<<<NB + NB * (NPTS / 64), 512, 0, stream>>>(xyz, feats, fps_idx, feats_t);
    ball_kernel<<<NB * NPOINT, 64, 0, stream>>>(xyz, fps_idx, ball_idx);
    mlp_kernel<<<NB * NPOINT, 64, 0, stream>>>(xyz, feats_t, fps_idx, ball_idx,
                                               W1, b1, W2, b2, W3, b3, out);
}